// Round 7
// baseline (48.898 us; speedup 1.0000x reference)
//
#include <hip/hip_runtime.h>
#include <math.h>

#define DD 1024
#define BB 8192

__device__ __forceinline__ float softplus_f(float x) {
    return fmaxf(x, 0.0f) + log1pf(expf(-fabsf(x)));
}

// ---------------- kernel A: partials of t[j] = sum_i softplus(rho[i,j])*eps[i]
// 256 blocks = 16 colgroups x 16 rowgroups, fully coalesced, no atomics.
__global__ __launch_bounds__(256) void k_t(const float* __restrict__ rho,
                                           const float* __restrict__ eps,
                                           float* __restrict__ part) {
    const int tx = threadIdx.x, lane = tx & 63, w = tx >> 6;
    const int cg = blockIdx.x & 15, rg = blockIdx.x >> 4;
    const int j = cg * 64 + lane;
    const int rowbase = rg * 64 + w * 16;
    float acc = 0.f;
#pragma unroll
    for (int k = 0; k < 16; ++k) {
        int row = rowbase + k;
        acc += softplus_f(rho[row * DD + j]) * eps[row];
    }
    __shared__ float red[4][64];
    red[w][lane] = acc;
    __syncthreads();
    if (tx < 64) {
        float s = red[0][tx] + red[1][tx] + red[2][tx] + red[3][tx];
        part[(cg * 64 + tx) * 16 + rg] = s;
    }
}

// ---------------- kernel B: u[i] = mu[i] + sum_j softplus(rho[i,j]) * t[j] ----
__global__ __launch_bounds__(256) void k_u(const float* __restrict__ rho,
                                           const float* __restrict__ mu,
                                           const float* __restrict__ part,
                                           float* __restrict__ u) {
    int i  = blockIdx.x;      // 1024 blocks
    int tx = threadIdx.x;
    float acc = 0.f;
#pragma unroll
    for (int c = 0; c < 4; ++c) {
        int j = tx + c * 256;
        const float4* p4 = (const float4*)(part + j * 16);
        float4 a = p4[0], b = p4[1], cc = p4[2], dd = p4[3];
        float tj = ((a.x + a.y) + (a.z + a.w)) + ((b.x + b.y) + (b.z + b.w)) +
                   ((cc.x + cc.y) + (cc.z + cc.w)) + ((dd.x + dd.y) + (dd.z + dd.w));
        acc += softplus_f(rho[i * DD + j]) * tj;
    }
#pragma unroll
    for (int off = 32; off > 0; off >>= 1)
        acc += __shfl_down(acc, off, 64);
    __shared__ float red[4];
    int lane = tx & 63, w = tx >> 6;
    if (lane == 0) red[w] = acc;
    __syncthreads();
    if (tx == 0) u[i] = mu[i] + red[0] + red[1] + red[2] + red[3];
}

// ---------------- main: out[d,b] = relu(s1*FWHT(u*FWHT(s2*x_b))/1024) ---------

template <int CTRL>
__device__ __forceinline__ float dppmov(float x) {
    return __int_as_float(
        __builtin_amdgcn_mov_dpp(__float_as_int(x), CTRL, 0xF, 0xF, true));
}

// Position mapping: lane l (bits l0..l5), reg m. p = 16*hi(l) + m with
//   h0=l0^l2 h1=l1^l2 h2=l2^l3 h3=l3 h4=l4 h5=l5
// cross-lane stages = lane XOR masks {1,2,7,15,16,32}. (R1-R3 validated form.)
__device__ __forceinline__ void fwht1024(float v[16], float sA, float sB,
                                         float sC, float sD, float sE, float sF) {
#pragma unroll
    for (int s = 1; s <= 8; s <<= 1) {
#pragma unroll
        for (int m = 0; m < 16; ++m)
            if ((m & s) == 0) {
                float a = v[m], b = v[m ^ s];
                v[m] = a + b;
                v[m ^ s] = a - b;
            }
    }
#pragma unroll
    for (int m = 0; m < 16; ++m) { float o = dppmov<0xB1>(v[m]);  v[m] = fmaf(v[m], sA, o); } // xor 1
#pragma unroll
    for (int m = 0; m < 16; ++m) { float o = dppmov<0x4E>(v[m]);  v[m] = fmaf(v[m], sB, o); } // xor 2
#pragma unroll
    for (int m = 0; m < 16; ++m) { float o = dppmov<0x141>(v[m]); v[m] = fmaf(v[m], sC, o); } // xor 7
#pragma unroll
    for (int m = 0; m < 16; ++m) { float o = dppmov<0x140>(v[m]); v[m] = fmaf(v[m], sD, o); } // xor 15
#pragma unroll
    for (int m = 0; m < 16; ++m) { float o = __shfl_xor(v[m], 16, 64); v[m] = fmaf(v[m], sE, o); } // xor 16
#pragma unroll
    for (int m = 0; m < 16; ++m) { float o = __shfl_xor(v[m], 32, 64); v[m] = fmaf(v[m], sF, o); } // xor 32
}

// 16 batches/block, 512 threads, f32 64KB tile, 2 blocks/CU, one row live per
// wave at a time (v[16] only, no spills under the 128-VGPR cap).
__global__ __launch_bounds__(512, 4) void k_main(const float* __restrict__ x,
                                                 const float* __restrict__ s1,
                                                 const float* __restrict__ s2,
                                                 const float* __restrict__ u,
                                                 float* __restrict__ out) {
    __shared__ __align__(16) float tile[16 * 1024];
    const int t    = threadIdx.x;
    const int lane = t & 63;
    const int wv   = t >> 6;
    const int b0   = blockIdx.x * 16;   // 512 blocks

    const int l0 = lane & 1, l1 = (lane >> 1) & 1, l2 = (lane >> 2) & 1,
              l3 = (lane >> 3) & 1, l4 = (lane >> 4) & 1, l5 = (lane >> 5) & 1;
    const int hi = (l0 ^ l2) | ((l1 ^ l2) << 1) | ((l2 ^ l3) << 2) | (l3 << 3) |
                   (l4 << 4) | (l5 << 5);
    const int base = hi << 4;

    const float sA = (l0 ^ l2) ? -1.f : 1.f;
    const float sB = (l1 ^ l2) ? -1.f : 1.f;
    const float sC = (l2 ^ l3) ? -1.f : 1.f;
    const float sD = l3 ? -1.f : 1.f;
    const float sE = l4 ? -1.f : 1.f;
    const float sF = l5 ? -1.f : 1.f;

    float4 s2f[4], uf[4], s1f[4];
#pragma unroll
    for (int c = 0; c < 4; ++c) {
        s2f[c] = *(const float4*)(s2 + base + 4 * c);
        uf[c]  = *(const float4*)(u  + base + 4 * c);
        s1f[c] = *(const float4*)(s1 + base + 4 * c);
        const float kscale = 1.0f / 1024.0f;   // fold 1/D into s1
        s1f[c].x *= kscale; s1f[c].y *= kscale;
        s1f[c].z *= kscale; s1f[c].w *= kscale;
    }
    const int qsw = hi & 3;   // chunk-level swizzle (keeps 16B contiguity)

    for (int rr = 0; rr < 2; ++rr) {
        const int r = wv * 2 + rr;
        const float* xr = x + (size_t)(b0 + r) * DD + base;
        float v[16];
#pragma unroll
        for (int c = 0; c < 4; ++c) {
            float4 xv = *(const float4*)(xr + 4 * c);
            v[4 * c + 0] = xv.x * s2f[c].x;
            v[4 * c + 1] = xv.y * s2f[c].y;
            v[4 * c + 2] = xv.z * s2f[c].z;
            v[4 * c + 3] = xv.w * s2f[c].w;
        }
        fwht1024(v, sA, sB, sC, sD, sE, sF);
#pragma unroll
        for (int c = 0; c < 4; ++c) {
            v[4 * c + 0] *= uf[c].x;
            v[4 * c + 1] *= uf[c].y;
            v[4 * c + 2] *= uf[c].z;
            v[4 * c + 3] *= uf[c].w;
        }
        fwht1024(v, sA, sB, sC, sD, sE, sF);
        // tile word for (row r, feature d=hi*16+m):
        //   r*1024 + ((hi ^ ((r>>2)&3))<<4) + 4*((m>>2)^qsw(hi)) + (m&3)
        // -> 4x ds_write_b128 per row; <=2-way bank aliasing (free).
        float* trow = tile + r * 1024 + ((hi ^ ((r >> 2) & 3)) << 4);
#pragma unroll
        for (int c = 0; c < 4; ++c) {
            float4 y;
            y.x = fmaxf(v[4 * c + 0] * s1f[c].x, 0.f);
            y.y = fmaxf(v[4 * c + 1] * s1f[c].y, 0.f);
            y.z = fmaxf(v[4 * c + 2] * s1f[c].z, 0.f);
            y.w = fmaxf(v[4 * c + 3] * s1f[c].w, 0.f);
            *(float4*)(trow + 4 * (c ^ qsw)) = y;
        }
    }
    __syncthreads();

    // transposed store: thread t -> feature d=(t>>2)+it*128, batches r4..r4+3.
#pragma unroll
    for (int it = 0; it < 8; ++it) {
        const int d  = (t >> 2) + (it << 7);
        const int r4 = (t & 3) << 2;
        const int h  = d >> 4;
        const int col = ((h ^ (t & 3)) << 4) + 4 * (((d >> 2) & 3) ^ (h & 3)) +
                        (d & 3);
        float4 y;
        y.x = tile[(r4 + 0) * 1024 + col];
        y.y = tile[(r4 + 1) * 1024 + col];
        y.z = tile[(r4 + 2) * 1024 + col];
        y.w = tile[(r4 + 3) * 1024 + col];
        *(float4*)(out + (size_t)d * BB + b0 + r4) = y;
    }
}

extern "C" void kernel_launch(void* const* d_in, const int* in_sizes, int n_in,
                              void* d_out, int out_size, void* d_ws, size_t ws_size,
                              hipStream_t stream) {
    const float* x   = (const float*)d_in[0];
    const float* s1  = (const float*)d_in[1];
    const float* s2  = (const float*)d_in[2];
    const float* mu  = (const float*)d_in[3];
    const float* rho = (const float*)d_in[4];
    const float* eps = (const float*)d_in[5];
    // d_in[6] = H unused: applied via fast Walsh-Hadamard transform.
    float* out = (float*)d_out;

    float* part = (float*)d_ws;      // [DD * 16] partials of t
    float* u    = part + DD * 16;    // [DD]

    k_t<<<256, 256, 0, stream>>>(rho, eps, part);
    k_u<<<DD, 256, 0, stream>>>(rho, mu, part, u);
    k_main<<<BB / 16, 512, 0, stream>>>(x, s1, s2, u, out);
    // INSTRUMENT (this round only): duplicate k_main. It deterministically
    // rewrites the same output; dur_us delta vs R6's 34.79 measures k_main
    // directly (L3-warm lower bound). Removed next round.
    k_main<<<BB / 16, 512, 0, stream>>>(x, s1, s2, u, out);
}

// Round 8
// 32.455 us; speedup vs baseline: 1.5066x; 1.5066x over previous
//
#include <hip/hip_runtime.h>
#include <math.h>

#define DD 1024
#define BB 8192

__device__ __forceinline__ float softplus_f(float x) {
    return fmaxf(x, 0.0f) + log1pf(expf(-fabsf(x)));
}

// ---------------- kernel A: partials of t[j] = sum_i softplus(rho[i,j])*eps[i]
// 256 blocks = 16 colgroups x 16 rowgroups, fully coalesced, no atomics.
__global__ __launch_bounds__(256) void k_t(const float* __restrict__ rho,
                                           const float* __restrict__ eps,
                                           float* __restrict__ part) {
    const int tx = threadIdx.x, lane = tx & 63, w = tx >> 6;
    const int cg = blockIdx.x & 15, rg = blockIdx.x >> 4;
    const int j = cg * 64 + lane;
    const int rowbase = rg * 64 + w * 16;
    float acc = 0.f;
#pragma unroll
    for (int k = 0; k < 16; ++k) {
        int row = rowbase + k;
        acc += softplus_f(rho[row * DD + j]) * eps[row];
    }
    __shared__ float red[4][64];
    red[w][lane] = acc;
    __syncthreads();
    if (tx < 64) {
        float s = red[0][tx] + red[1][tx] + red[2][tx] + red[3][tx];
        part[(cg * 64 + tx) * 16 + rg] = s;
    }
}

// ---------------- kernel B: u[i] = mu[i] + sum_j softplus(rho[i,j]) * t[j] ----
__global__ __launch_bounds__(256) void k_u(const float* __restrict__ rho,
                                           const float* __restrict__ mu,
                                           const float* __restrict__ part,
                                           float* __restrict__ u) {
    int i  = blockIdx.x;      // 1024 blocks
    int tx = threadIdx.x;
    float acc = 0.f;
#pragma unroll
    for (int c = 0; c < 4; ++c) {
        int j = tx + c * 256;
        const float4* p4 = (const float4*)(part + j * 16);
        float4 a = p4[0], b = p4[1], cc = p4[2], dd = p4[3];
        float tj = ((a.x + a.y) + (a.z + a.w)) + ((b.x + b.y) + (b.z + b.w)) +
                   ((cc.x + cc.y) + (cc.z + cc.w)) + ((dd.x + dd.y) + (dd.z + dd.w));
        acc += softplus_f(rho[i * DD + j]) * tj;
    }
#pragma unroll
    for (int off = 32; off > 0; off >>= 1)
        acc += __shfl_down(acc, off, 64);
    __shared__ float red[4];
    int lane = tx & 63, w = tx >> 6;
    if (lane == 0) red[w] = acc;
    __syncthreads();
    if (tx == 0) u[i] = mu[i] + red[0] + red[1] + red[2] + red[3];
}

// ---------------- main: out[d,b] = relu(s1*FWHT(u*FWHT(s2*x_b))/1024) ---------

template <int CTRL>
__device__ __forceinline__ float dppmov(float x) {
    return __int_as_float(
        __builtin_amdgcn_mov_dpp(__float_as_int(x), CTRL, 0xF, 0xF, true));
}

// Position mapping: lane l (bits l0..l5), reg m. p = 16*hi(l) + m with
//   h0=l0^l2 h1=l1^l2 h2=l2^l3 h3=l3 h4=l4 h5=l5
// cross-lane stages = lane XOR masks {1,2,7,15,16,32}. (R1-R3 validated form.)
__device__ __forceinline__ void fwht1024(float v[16], float sA, float sB,
                                         float sC, float sD, float sE, float sF) {
#pragma unroll
    for (int s = 1; s <= 8; s <<= 1) {
#pragma unroll
        for (int m = 0; m < 16; ++m)
            if ((m & s) == 0) {
                float a = v[m], b = v[m ^ s];
                v[m] = a + b;
                v[m ^ s] = a - b;
            }
    }
#pragma unroll
    for (int m = 0; m < 16; ++m) { float o = dppmov<0xB1>(v[m]);  v[m] = fmaf(v[m], sA, o); } // xor 1
#pragma unroll
    for (int m = 0; m < 16; ++m) { float o = dppmov<0x4E>(v[m]);  v[m] = fmaf(v[m], sB, o); } // xor 2
#pragma unroll
    for (int m = 0; m < 16; ++m) { float o = dppmov<0x141>(v[m]); v[m] = fmaf(v[m], sC, o); } // xor 7
#pragma unroll
    for (int m = 0; m < 16; ++m) { float o = dppmov<0x140>(v[m]); v[m] = fmaf(v[m], sD, o); } // xor 15
#pragma unroll
    for (int m = 0; m < 16; ++m) { float o = __shfl_xor(v[m], 16, 64); v[m] = fmaf(v[m], sE, o); } // xor 16
#pragma unroll
    for (int m = 0; m < 16; ++m) { float o = __shfl_xor(v[m], 32, 64); v[m] = fmaf(v[m], sF, o); } // xor 32
}

// 16 batches/block, 512 threads, f32 64KB tile, 2 blocks/CU, one row live per
// wave at a time. Block->batch map pairs the two blocks sharing each 128B
// output line onto the SAME XCD (XCD = bid%8; bid and bid+8 share an XCD),
// so partial 64B writes merge to full lines in that XCD's L2.
__global__ __launch_bounds__(512, 4) void k_main(const float* __restrict__ x,
                                                 const float* __restrict__ s1,
                                                 const float* __restrict__ s2,
                                                 const float* __restrict__ u,
                                                 float* __restrict__ out) {
    __shared__ __align__(16) float tile[16 * 1024];
    const int t    = threadIdx.x;
    const int lane = t & 63;
    const int wv   = t >> 6;
    const int bid  = blockIdx.x;        // 512 blocks
    const int x8   = bid & 7;           // XCD (assumed bid%8 round-robin)
    const int q    = bid >> 3;          // 0..63
    const int pair = x8 * 32 + (q >> 1);        // 0..255, same for q=2k,2k+1
    const int b0   = pair * 32 + (q & 1) * 16;  // bijective over {0,16,..,8176}

    const int l0 = lane & 1, l1 = (lane >> 1) & 1, l2 = (lane >> 2) & 1,
              l3 = (lane >> 3) & 1, l4 = (lane >> 4) & 1, l5 = (lane >> 5) & 1;
    const int hi = (l0 ^ l2) | ((l1 ^ l2) << 1) | ((l2 ^ l3) << 2) | (l3 << 3) |
                   (l4 << 4) | (l5 << 5);
    const int base = hi << 4;

    const float sA = (l0 ^ l2) ? -1.f : 1.f;
    const float sB = (l1 ^ l2) ? -1.f : 1.f;
    const float sC = (l2 ^ l3) ? -1.f : 1.f;
    const float sD = l3 ? -1.f : 1.f;
    const float sE = l4 ? -1.f : 1.f;
    const float sF = l5 ? -1.f : 1.f;

    float4 s2f[4], uf[4], s1f[4];
#pragma unroll
    for (int c = 0; c < 4; ++c) {
        s2f[c] = *(const float4*)(s2 + base + 4 * c);
        uf[c]  = *(const float4*)(u  + base + 4 * c);
        s1f[c] = *(const float4*)(s1 + base + 4 * c);
        const float kscale = 1.0f / 1024.0f;   // fold 1/D into s1
        s1f[c].x *= kscale; s1f[c].y *= kscale;
        s1f[c].z *= kscale; s1f[c].w *= kscale;
    }
    const int qsw = hi & 3;   // chunk-level swizzle (keeps 16B contiguity)

    for (int rr = 0; rr < 2; ++rr) {
        const int r = wv * 2 + rr;
        const float* xr = x + (size_t)(b0 + r) * DD + base;
        float v[16];
#pragma unroll
        for (int c = 0; c < 4; ++c) {
            float4 xv = *(const float4*)(xr + 4 * c);
            v[4 * c + 0] = xv.x * s2f[c].x;
            v[4 * c + 1] = xv.y * s2f[c].y;
            v[4 * c + 2] = xv.z * s2f[c].z;
            v[4 * c + 3] = xv.w * s2f[c].w;
        }
        fwht1024(v, sA, sB, sC, sD, sE, sF);
#pragma unroll
        for (int c = 0; c < 4; ++c) {
            v[4 * c + 0] *= uf[c].x;
            v[4 * c + 1] *= uf[c].y;
            v[4 * c + 2] *= uf[c].z;
            v[4 * c + 3] *= uf[c].w;
        }
        fwht1024(v, sA, sB, sC, sD, sE, sF);
        // tile word for (row r, feature d=hi*16+m):
        //   r*1024 + ((hi ^ ((r>>2)&3))<<4) + 4*((m>>2)^qsw(hi)) + (m&3)
        // -> 4x ds_write_b128 per row; <=2-way bank aliasing (free).
        float* trow = tile + r * 1024 + ((hi ^ ((r >> 2) & 3)) << 4);
#pragma unroll
        for (int c = 0; c < 4; ++c) {
            float4 y;
            y.x = fmaxf(v[4 * c + 0] * s1f[c].x, 0.f);
            y.y = fmaxf(v[4 * c + 1] * s1f[c].y, 0.f);
            y.z = fmaxf(v[4 * c + 2] * s1f[c].z, 0.f);
            y.w = fmaxf(v[4 * c + 3] * s1f[c].w, 0.f);
            *(float4*)(trow + 4 * (c ^ qsw)) = y;
        }
    }
    __syncthreads();

    // transposed store: thread t -> feature d=(t>>2)+it*128, batches r4..r4+3.
#pragma unroll
    for (int it = 0; it < 8; ++it) {
        const int d  = (t >> 2) + (it << 7);
        const int r4 = (t & 3) << 2;
        const int h  = d >> 4;
        const int col = ((h ^ (t & 3)) << 4) + 4 * (((d >> 2) & 3) ^ (h & 3)) +
                        (d & 3);
        float4 y;
        y.x = tile[(r4 + 0) * 1024 + col];
        y.y = tile[(r4 + 1) * 1024 + col];
        y.z = tile[(r4 + 2) * 1024 + col];
        y.w = tile[(r4 + 3) * 1024 + col];
        *(float4*)(out + (size_t)d * BB + b0 + r4) = y;
    }
}

extern "C" void kernel_launch(void* const* d_in, const int* in_sizes, int n_in,
                              void* d_out, int out_size, void* d_ws, size_t ws_size,
                              hipStream_t stream) {
    const float* x   = (const float*)d_in[0];
    const float* s1  = (const float*)d_in[1];
    const float* s2  = (const float*)d_in[2];
    const float* mu  = (const float*)d_in[3];
    const float* rho = (const float*)d_in[4];
    const float* eps = (const float*)d_in[5];
    // d_in[6] = H unused: applied via fast Walsh-Hadamard transform.
    float* out = (float*)d_out;

    float* part = (float*)d_ws;      // [DD * 16] partials of t
    float* u    = part + DD * 16;    // [DD]

    k_t<<<256, 256, 0, stream>>>(rho, eps, part);
    k_u<<<DD, 256, 0, stream>>>(rho, mu, part, u);
    k_main<<<BB / 16, 512, 0, stream>>>(x, s1, s2, u, out);
}